// Round 6
// baseline (140.574 us; speedup 1.0000x reference)
//
#include <hip/hip_runtime.h>
#include <hip/hip_bf16.h>

typedef __bf16 bf16;
typedef __bf16 bf16x2 __attribute__((ext_vector_type(2)));
typedef __bf16 bf16x8 __attribute__((ext_vector_type(8)));
typedef float f32x4 __attribute__((ext_vector_type(4)));
typedef int i32x4 __attribute__((ext_vector_type(4)));

#define B_ 8
#define N_ 1024
#define C_ 256
#define H_ 8
#define C3_ 768
#define SCALE 0.17677669529663689f  // 1/sqrt(32), pre-folded into q
#define FMAX 16.0f                  // fixed softmax max, pre-folded into ebtl

// ws layout:
//   Wq_tiled [8 kt][12 nt][64 n][32 k]   393216 B  @ 0
//   Wp_tiled [8 kt][256 n][32 k]         131072 B  @ 393216
//   q  [8192][256] (pre-scaled by SCALE) 4 MiB     @ 524288
//   kT [b][h][1024 n][32 d]              4 MiB     @ 4718592
//   vT [b][c=h*32+d][1024 n']            4 MiB     @ 8912896
//   rel8 [b][i][j] int8                  8 MiB     @ 13107200
// vT perm (matches swapped-QK P fragment, k-slot = quad*8+e):
//   n' = (n&~31) | ((n&12)<<1) | (n&3) | (((n>>4)&1)<<2)

// ---------------------------------------------------------------------------
// prep: weight tiling (one-off, tiny) + rel int32 -> int8 pack (8M elems).
// ---------------------------------------------------------------------------
__global__ __launch_bounds__(256) void prep(
    const float* __restrict__ Wqkv, const float* __restrict__ Wproj,
    const int* __restrict__ rel,
    bf16* __restrict__ Wq_tiled, bf16* __restrict__ Wp_tiled,
    unsigned char* __restrict__ rel8)
{
  int bb = blockIdx.x;
  if (bb < 768) {
    int o = bb * 256 + threadIdx.x;
    int kk = o & 31;
    int idx = o >> 5;
    int nr = idx & 63;
    int qq = idx >> 6;            // kt*12 + nt
    int nt = qq % 12, kt = qq / 12;
    int n = nt * 64 + nr, k = kt * 32 + kk;
    Wq_tiled[o] = (bf16)Wqkv[k * C3_ + n];
  } else if (bb < 1024) {
    int p = (bb - 768) * 256 + threadIdx.x;
    int kk = p & 31;
    int n = (p >> 5) & 255;
    int kt = p >> 13;
    int k = kt * 32 + kk;
    Wp_tiled[p] = (bf16)Wproj[k * C_ + n];
  } else {
    // rel pack: 2048 blocks x 256 thr x 16 elems
    long p = ((long)(bb - 1024) * 256 + threadIdx.x) * 16;
    i32x4 a = *reinterpret_cast<const i32x4*>(rel + p);
    i32x4 b2 = *reinterpret_cast<const i32x4*>(rel + p + 4);
    i32x4 c = *reinterpret_cast<const i32x4*>(rel + p + 8);
    i32x4 d = *reinterpret_cast<const i32x4*>(rel + p + 12);
    unsigned o0 = (unsigned)a[0] | ((unsigned)a[1] << 8) | ((unsigned)a[2] << 16) | ((unsigned)a[3] << 24);
    unsigned o1 = (unsigned)b2[0] | ((unsigned)b2[1] << 8) | ((unsigned)b2[2] << 16) | ((unsigned)b2[3] << 24);
    unsigned o2 = (unsigned)c[0] | ((unsigned)c[1] << 8) | ((unsigned)c[2] << 16) | ((unsigned)c[3] << 24);
    unsigned o3 = (unsigned)d[0] | ((unsigned)d[1] << 8) | ((unsigned)d[2] << 16) | ((unsigned)d[3] << 24);
    i32x4 ov = {(int)o0, (int)o1, (int)o2, (int)o3};
    *reinterpret_cast<i32x4*>(rel8 + p) = ov;
  }
}

// ---------------------------------------------------------------------------
// QKV projection, 128x128 block tile (m93-class): 4 waves, each 64x64 via
// 4x4 f32x4 accumulators -> 16 MFMA per 8 ds_read_b128 per k-step.
// ---------------------------------------------------------------------------
__global__ __launch_bounds__(256) void gemm_qkv(
    const float* __restrict__ A, const bf16* __restrict__ Wq_tiled,
    bf16* __restrict__ q, bf16* __restrict__ kT, bf16* __restrict__ vT)
{
  __shared__ bf16 As[128][40];
  __shared__ bf16 Bts[128][40];   // Bts[n][k]
  __shared__ bf16 Vls[64][136];   // v-epilogue transpose buffer (64ch x 128n)

  int tid = threadIdx.x;
  int wave = tid >> 6, lane = tid & 63, quad = lane >> 4, l16 = lane & 15;
  int m0 = blockIdx.x * 128, n0 = blockIdx.y * 128;
  int msub = (wave & 1) * 64, nsub = (wave >> 1) * 64;

  f32x4 acc[4][4] = {};

  int arow = tid >> 1, akc = (tid & 1) * 16;
  const float* aptr = A + (long)(m0 + arow) * C_ + akc;   // + k0
  int bn = tid >> 1, bkc = (tid & 1) * 16;
  const bf16* bptr = Wq_tiled +
      ((long)(blockIdx.y * 2 + (bn >> 6)) * 2048 + (bn & 63) * 32 + bkc);

  float4 a0 = *reinterpret_cast<const float4*>(aptr);
  float4 a1 = *reinterpret_cast<const float4*>(aptr + 4);
  float4 a2 = *reinterpret_cast<const float4*>(aptr + 8);
  float4 a3 = *reinterpret_cast<const float4*>(aptr + 12);
  i32x4 bv0 = *reinterpret_cast<const i32x4*>(bptr);
  i32x4 bv1 = *reinterpret_cast<const i32x4*>(bptr + 8);

  for (int kt = 0; kt < 8; ++kt) {
    __syncthreads();
    {
      bf16 at[16] = {(bf16)a0.x, (bf16)a0.y, (bf16)a0.z, (bf16)a0.w,
                     (bf16)a1.x, (bf16)a1.y, (bf16)a1.z, (bf16)a1.w,
                     (bf16)a2.x, (bf16)a2.y, (bf16)a2.z, (bf16)a2.w,
                     (bf16)a3.x, (bf16)a3.y, (bf16)a3.z, (bf16)a3.w};
      *reinterpret_cast<bf16x8*>(&As[arow][akc]) = *reinterpret_cast<bf16x8*>(at);
      *reinterpret_cast<bf16x8*>(&As[arow][akc + 8]) = *reinterpret_cast<bf16x8*>(at + 8);
      *reinterpret_cast<i32x4*>(&Bts[bn][bkc]) = bv0;
      *reinterpret_cast<i32x4*>(&Bts[bn][bkc + 8]) = bv1;
    }
    __syncthreads();

    if (kt < 7) {
      int kn = (kt + 1) * 32;
      a0 = *reinterpret_cast<const float4*>(aptr + kn);
      a1 = *reinterpret_cast<const float4*>(aptr + kn + 4);
      a2 = *reinterpret_cast<const float4*>(aptr + kn + 8);
      a3 = *reinterpret_cast<const float4*>(aptr + kn + 12);
      bv0 = *reinterpret_cast<const i32x4*>(bptr + (long)(kt + 1) * 24576);
      bv1 = *reinterpret_cast<const i32x4*>(bptr + (long)(kt + 1) * 24576 + 8);
    }

    bf16x8 af[4], bfr[4];
#pragma unroll
    for (int mi = 0; mi < 4; ++mi)
      af[mi] = *reinterpret_cast<const bf16x8*>(&As[msub + mi * 16 + l16][quad * 8]);
#pragma unroll
    for (int ni = 0; ni < 4; ++ni)
      bfr[ni] = *reinterpret_cast<const bf16x8*>(&Bts[nsub + ni * 16 + l16][quad * 8]);
#pragma unroll
    for (int mi = 0; mi < 4; ++mi)
#pragma unroll
      for (int ni = 0; ni < 4; ++ni)
        acc[mi][ni] = __builtin_amdgcn_mfma_f32_16x16x32_bf16(af[mi], bfr[ni], acc[mi][ni], 0, 0, 0);
  }

  if (n0 < 256) {
#pragma unroll
    for (int mi = 0; mi < 4; ++mi)
#pragma unroll
      for (int ni = 0; ni < 4; ++ni)
#pragma unroll
        for (int r = 0; r < 4; ++r) {
          int row = m0 + msub + mi * 16 + quad * 4 + r;
          int col = n0 + nsub + ni * 16 + l16;
          q[(long)row * 256 + col] = (bf16)(acc[mi][ni][r] * SCALE);
        }
  } else if (n0 < 512) {
#pragma unroll
    for (int mi = 0; mi < 4; ++mi)
#pragma unroll
      for (int ni = 0; ni < 4; ++ni)
#pragma unroll
        for (int r = 0; r < 4; ++r) {
          int row = m0 + msub + mi * 16 + quad * 4 + r;
          int c = n0 + nsub + ni * 16 + l16 - 256;
          int b = row >> 10, n = row & 1023;
          int h = c >> 5, d = c & 31;
          kT[(((long)(b * H_ + h)) * N_ + n) * 32 + d] = (bf16)acc[mi][ni][r];
        }
  } else {
    int b = m0 >> 10;
#pragma unroll
    for (int ch = 0; ch < 2; ++ch) {
      __syncthreads();
      if ((nsub >> 6) == ch) {
#pragma unroll
        for (int mi = 0; mi < 4; ++mi)
#pragma unroll
          for (int ni = 0; ni < 4; ++ni)
#pragma unroll
            for (int r = 0; r < 4; ++r) {
              int cc = ni * 16 + l16;                  // 0..63 within half
              int nn = msub + mi * 16 + quad * 4 + r;  // 0..127
              // swapped-QK PV fragment perm
              int np = (nn & 96) | ((nn & 12) << 1) | (nn & 3) | (((nn >> 4) & 1) << 2);
              Vls[cc][np] = (bf16)acc[mi][ni][r];
            }
      }
      __syncthreads();
      int cc = tid >> 2, nseg = (tid & 3) * 32;
      long base = ((long)(b * C_ + (n0 - 512) + ch * 64 + cc)) * N_ + (m0 & 1023) + nseg;
#pragma unroll
      for (int j = 0; j < 4; ++j)
        *reinterpret_cast<i32x4*>(vT + base + j * 8) =
            *reinterpret_cast<const i32x4*>(&Vls[cc][nseg + j * 8]);
    }
  }
}

// ---------------------------------------------------------------------------
// Flash attention + fused projection — swapped-QK register softmax, DMA
// staging, and a BARRIER-FREE j-loop: K, V, AND rel8 are all staged
// WAVE-PRIVATELY by global_load_lds, so the only ordering primitive in the
// loop is each wave's own counted vmcnt(8) — waves drift freely, hiding
// each other's stalls (4 waves/SIMD). rel8 is int8-packed by prep (512B
// per wave-tile): LDS = K[2][8][2048] + V[2][8][2048] + rel8[3][8][512]
// + ebtl = 78336 B -> 2 blocks/CU. KV 1-tile DMA cover, rel8 2-tile cover,
// rel8 read-ahead 1 tile + gather 1 tile ahead of use.
// ---------------------------------------------------------------------------
__global__ __launch_bounds__(512) void flash_attn(
    const bf16* __restrict__ q, const bf16* __restrict__ kT,
    const bf16* __restrict__ vT, const unsigned char* __restrict__ rel8,
    const int* __restrict__ rel_len, const float* __restrict__ btab,
    const bf16* __restrict__ Wp_tiled, const float* __restrict__ bias,
    float* __restrict__ out)
{
  __shared__ __align__(16) char smem[78336];
  char* const KB0 = smem;            // [2][8][2048]
  char* const VB0 = smem + 32768;    // [2][8][2048]
  char* const RB0 = smem + 65536;    // [3][8][512]
  float* const ebtl = (float*)(smem + 77824);  // [8][16]

  int tid = threadIdx.x;
  int h = tid >> 6, lane = tid & 63, quad = lane >> 4, l16 = lane & 15;

  // bijective XCD swizzle (512 blocks = 8 XCDs x 64): XCD k -> batch k.
  int wg = blockIdx.y * 64 + blockIdx.x;
  int swz = (wg & 7) * 64 + (wg >> 3);
  int b = swz >> 6, i0 = (swz & 63) * 16;
  long bN = (long)b * N_;

  int mask_len = (int)((float)rel_len[b] * 0.5f);
  if (tid < 80) {
    int t = tid >> 3, hh = tid & 7;
    ebtl[hh * 16 + t] = __expf(btab[t * H_ + hh] + (t > mask_len ? -100.f : 0.f) - FMAX);
  }

  // Q as B-fragment: col = q-row (l16), k = d (quad*8+e)
  bf16x8 qf = *reinterpret_cast<const bf16x8*>(
      q + (bN + i0 + l16) * 256 + h * 32 + quad * 8);

  // ebtl visible + all prologue VMEM (qf/btab/rel_len) drained, so the loop's
  // vmcnt counts ONLY the staging DMAs.
  __syncthreads();

  // ---- per-lane DMA source offsets (16B-slot swizzle pre-applied) ----
  int l = lane;
  int sxc = (((l & 3) ^ ((l >> 3) & 3)) << 4);
  int kc0 = (l >> 2) * 64 + sxc;                  // K: row l>>2, 2nd GLD +1024
  int vc0 = (h * 32 + (l >> 2)) * 2048 + sxc;     // V: chan h*32+(l>>2), 2nd +32768
  int rc0 = (l >> 3) * 1024 + (l & 7) * 4;        // rel8: row l>>3, 2nd GLD +8192

  const char* kTb = (const char*)kT + ((long)(b * 8 + h) << 16);  // +t*2048
  const char* vTb = (const char*)vT + (long)b * 524288;           // +t*64
  const char* rb8 = (const char*)rel8 + (bN + i0) * 1024;         // +t*32

  // ---- LDS read offsets ----
  int swq = ((quad ^ ((l16 >> 1) & 3)) << 4);
  int kr = h * 2048 + l16 * 64 + swq;   // K/V: row l16 (+1024: row 16+l16)
  int rr = h * 512 + l16 * 32 + quad * 4;  // rel8: row l16, j=4q (+16: j=16+4q)

#define KB(i) (KB0 + (i) * 16384)
#define VB(i) (VB0 + (i) * 16384)
#define RB(i) (RB0 + (i) * 4096)

#define GLD16(G, L) __builtin_amdgcn_global_load_lds(                         \
    (const __attribute__((address_space(1))) void*)(G),                       \
    (__attribute__((address_space(3))) void*)(L), 16, 0, 0)
#define GLD4(G, L) __builtin_amdgcn_global_load_lds(                          \
    (const __attribute__((address_space(1))) void*)(G),                       \
    (__attribute__((address_space(3))) void*)(L), 4, 0, 0)

#define GATH(G, RV0, RV1) do {                                                \
    _Pragma("unroll")                                                         \
    for (int e = 0; e < 4; ++e) {                                             \
      G[e]     = ebtl[h * 16 + (int)((RV0 >> (8 * e)) & 255u)];               \
      G[4 + e] = ebtl[h * 16 + (int)((RV1 >> (8 * e)) & 255u)];               \
    }                                                                         \
  } while (0)

#define COMP(K0, K1, V0, V1, G) do {                                          \
    f32x4 z = {};                                                             \
    f32x4 s0 = __builtin_amdgcn_mfma_f32_16x16x32_bf16(K0, qf, z, 0, 0, 0);   \
    f32x4 s1 = __builtin_amdgcn_mfma_f32_16x16x32_bf16(K1, qf, z, 0, 0, 0);   \
    bf16x8 pa;                                                                \
    _Pragma("unroll")                                                         \
    for (int e = 0; e < 4; ++e) {                                             \
      float p0 = __expf(s0[e]) * G[e];                                        \
      float p1 = __expf(s1[e]) * G[4 + e];                                    \
      l_acc += p0 + p1;                                                       \
      pa[e] = (bf16)p0;                                                       \
      pa[4 + e] = (bf16)p1;                                                   \
    }                                                                         \
    oacc[0] = __builtin_amdgcn_mfma_f32_16x16x32_bf16(pa, V0, oacc[0], 0, 0, 0); \
    oacc[1] = __builtin_amdgcn_mfma_f32_16x16x32_bf16(pa, V1, oacc[1], 0, 0, 0); \
  } while (0)

// Tile T: issue KV(T+1)->buf KVW, rel8(T+3)->buf RW_; counted wait (own wave
// only!); read KV(T) from KVR + read-ahead rel8(T+1) from RR_; gather GN for
// T+1; compute T with GC. No barriers.
#define TILE(T_, KVR, KVW, RR_, RW_, GC, GN) do {                             \
    int tn_ = ((T_) + 1) & 31, tr_ = ((T_) + 3) & 31;                         \
    GLD16(kTb + tn_ * 2048 + kc0,        KB(KVW) + h * 2048);                 \
    GLD16(kTb + tn_ * 2048 + kc0 + 1024, KB(KVW) + h * 2048 + 1024);          \
    GLD16(vTb + tn_ * 64 + vc0,          VB(KVW) + h * 2048);                 \
    GLD16(vTb + tn_ * 64 + vc0 + 32768,  VB(KVW) + h * 2048 + 1024);          \
    GLD4(rb8 + tr_ * 32 + rc0,           RB(RW_) + h * 512);                  \
    GLD4(rb8 + tr_ * 32 + rc0 + 8192,    RB(RW_) + h * 512 + 256);            \
    asm volatile("s_waitcnt vmcnt(8)" ::: "memory");                          \
    bf16x8 kf0 = *(const bf16x8*)(KB(KVR) + kr);                              \
    bf16x8 kf1 = *(const bf16x8*)(KB(KVR) + kr + 1024);                       \
    bf16x8 vf0 = *(const bf16x8*)(VB(KVR) + kr);                              \
    bf16x8 vf1 = *(const bf16x8*)(VB(KVR) + kr + 1024);                       \
    unsigned rv0 = *(const unsigned*)(RB(RR_) + rr);                          \
    unsigned rv1 = *(const unsigned*)(RB(RR_) + rr + 16);                     \
    GATH(GN, rv0, rv1);                                                       \
    COMP(kf0, kf1, vf0, vf1, GC);                                             \
  } while (0)

  f32x4 oacc[2] = {};
  float l_acc = 0.f;
  float gA[8], gB[8];

  // ---- prologue: KV(0)->buf0; rel8(0,1,2)->rbuf 0,1,2; gather gA(0).
  GLD16(kTb + kc0,        KB(0) + h * 2048);
  GLD16(kTb + kc0 + 1024, KB(0) + h * 2048 + 1024);
  GLD16(vTb + vc0,          VB(0) + h * 2048);
  GLD16(vTb + vc0 + 32768,  VB(0) + h * 2048 + 1024);
  GLD4(rb8 + rc0,             RB(0) + h * 512);
  GLD4(rb8 + rc0 + 8192,      RB(0) + h * 512 + 256);
  GLD4(rb8 + 32 + rc0,        RB(1) + h * 512);
  GLD4(rb8 + 32 + rc0 + 8192, RB(1) + h * 512 + 256);
  GLD4(rb8 + 64 + rc0,        RB(2) + h * 512);
  GLD4(rb8 + 64 + rc0 + 8192, RB(2) + h * 512 + 256);
  asm volatile("s_waitcnt vmcnt(2)" ::: "memory");  // KV(0), rel8(0), rel8(1) done
  {
    unsigned rv0 = *(const unsigned*)(RB(0) + rr);
    unsigned rv1 = *(const unsigned*)(RB(0) + rr + 16);
    GATH(gA, rv0, rv1);
  }

  // KV bufs: (T&1 read, (T+1)&1 write); rel8: read-ahead (T+1)%3, write (T+3)%3.
#pragma unroll 1
  for (int t = 0; t < 30; t += 6) {
    TILE(t + 0, 0, 1, 1, 0, gA, gB);
    TILE(t + 1, 1, 0, 2, 1, gB, gA);
    TILE(t + 2, 0, 1, 0, 2, gA, gB);
    TILE(t + 3, 1, 0, 1, 0, gB, gA);
    TILE(t + 4, 0, 1, 2, 1, gA, gB);
    TILE(t + 5, 1, 0, 0, 2, gB, gA);
  }
  TILE(30, 0, 1, 1, 0, gA, gB);
  TILE(31, 1, 0, 2, 1, gB, gA);
#undef TILE
#undef COMP
#undef GATH
#undef GLD16
#undef GLD4
#undef KB
#undef VB
#undef RB

  // drain wrapped tail DMAs before aliasing smem as attL
  asm volatile("s_waitcnt vmcnt(0)" ::: "memory");
  __syncthreads();

  // row sums: lane's p's are all for q-row l16 -> reduce across quads.
  float lsum = l_acc;
  lsum += __shfl_xor(lsum, 16);
  lsum += __shfl_xor(lsum, 32);
  float inv = 1.f / lsum;   // inv for q-row = l16

  bf16 (*attL)[264] = (bf16(*)[264])(void*)smem;
#pragma unroll
  for (int r = 0; r < 4; ++r) {
    float invr = __shfl(inv, quad * 4 + r);
    attL[quad * 4 + r][h * 32 + l16] = (bf16)(oacc[0][r] * invr);
    attL[quad * 4 + r][h * 32 + 16 + l16] = (bf16)(oacc[1][r] * invr);
  }
  __syncthreads();

  // fused projection: wave h computes out[16 rows][h*32 .. h*32+31]
  f32x4 pacc[2] = {};
  const bf16* wp = Wp_tiled + ((h * 32 + l16) * 32 + quad * 8);  // + kt*8192, +512 for ni=1
#pragma unroll
  for (int kt = 0; kt < 8; ++kt) {
    bf16x8 afr = *reinterpret_cast<const bf16x8*>(&attL[l16][kt * 32 + quad * 8]);
    bf16x8 b0 = *reinterpret_cast<const bf16x8*>(wp + kt * 8192);
    bf16x8 b1 = *reinterpret_cast<const bf16x8*>(wp + kt * 8192 + 512);
    pacc[0] = __builtin_amdgcn_mfma_f32_16x16x32_bf16(afr, b0, pacc[0], 0, 0, 0);
    pacc[1] = __builtin_amdgcn_mfma_f32_16x16x32_bf16(afr, b1, pacc[1], 0, 0, 0);
  }
  float bi0 = bias[h * 32 + l16];
  float bi1 = bias[h * 32 + 16 + l16];
#pragma unroll
  for (int r = 0; r < 4; ++r) {
    long rowoff = (bN + i0 + quad * 4 + r) * C_ + h * 32;
    out[rowoff + l16] = pacc[0][r] + bi0;
    out[rowoff + 16 + l16] = pacc[1][r] + bi1;
  }
}

// ---------------------------------------------------------------------------
extern "C" void kernel_launch(void* const* d_in, const int* in_sizes, int n_in,
                              void* d_out, int out_size, void* d_ws, size_t ws_size,
                              hipStream_t stream) {
  const float* X     = (const float*)d_in[0];   // att_embedding [8,1024,256] fp32
  const int*   rel   = (const int*)d_in[1];     // relation_position [8,1024,1024]
  const int*   rlen  = (const int*)d_in[2];     // rel_len [8]
  const float* Wqkv  = (const float*)d_in[3];   // [256,768] fp32
  const float* Wproj = (const float*)d_in[4];   // [256,256] fp32
  const float* bproj = (const float*)d_in[5];   // [256] fp32
  const float* btab  = (const float*)d_in[6];   // [10,8] fp32
  float* out = (float*)d_out;                   // [8,1024,256] fp32

  char* ws = (char*)d_ws;
  bf16* Wq_tiled = (bf16*)ws;                            // 393216 B
  bf16* Wp_tiled = (bf16*)(ws + 393216);                 // 131072 B
  bf16* q  = (bf16*)(ws + 524288);                       // 4 MiB
  bf16* kT = (bf16*)(ws + 524288 + 4194304);             // 4 MiB
  bf16* vT = (bf16*)(ws + 524288 + 2 * 4194304);         // 4 MiB
  unsigned char* rel8 = (unsigned char*)(ws + 13107200); // 8 MiB

  prep<<<dim3(3072), 256, 0, stream>>>(Wqkv, Wproj, rel, Wq_tiled, Wp_tiled, rel8);
  gemm_qkv<<<dim3(8192 / 128, C3_ / 128), 256, 0, stream>>>(X, Wq_tiled, q, kT, vT);
  flash_attn<<<dim3(N_ / 16, B_), 512, 0, stream>>>(
      q, kT, vT, rel8, rlen, btab, Wp_tiled, bproj, out);
}

// Round 8
// 138.797 us; speedup vs baseline: 1.0128x; 1.0128x over previous
//
#include <hip/hip_runtime.h>
#include <hip/hip_bf16.h>

typedef __bf16 bf16;
typedef __bf16 bf16x2 __attribute__((ext_vector_type(2)));
typedef __bf16 bf16x8 __attribute__((ext_vector_type(8)));
typedef float f32x4 __attribute__((ext_vector_type(4)));
typedef int i32x4 __attribute__((ext_vector_type(4)));

#define B_ 8
#define N_ 1024
#define C_ 256
#define H_ 8
#define C3_ 768
#define SCALE 0.17677669529663689f  // 1/sqrt(32), pre-folded into q
#define FMAX 16.0f                  // fixed softmax max, pre-folded into ebtl

// ws layout:
//   Wq_tiled [8 kt][12 nt][64 n][32 k]   393216 B  @ 0
//   Wp_tiled [8 kt][256 n][32 k]         131072 B  @ 393216
//   q  [8192][256] (pre-scaled by SCALE) 4 MiB     @ 524288
//   kT [b][h][1024 n][32 d]              4 MiB     @ 4718592
//   vT [b][c=h*32+d][1024 n']            4 MiB     @ 8912896
//   rel8 [b][i][j] int8                  8 MiB     @ 13107200
// vT perm (matches swapped-QK P fragment, k-slot = quad*8+e):
//   n' = (n&~31) | ((n&12)<<1) | (n&3) | (((n>>4)&1)<<2)

// ---------------------------------------------------------------------------
// prep: Wq tiling only (Wp tiling + rel8 pack ride along in gemm_qkv's
// launch — they feed flash, not gemm, so no dependency).
// ---------------------------------------------------------------------------
__global__ __launch_bounds__(256) void prep(
    const float* __restrict__ Wqkv, bf16* __restrict__ Wq_tiled)
{
  int o = blockIdx.x * 256 + threadIdx.x;
  int kk = o & 31;
  int idx = o >> 5;
  int nr = idx & 63;
  int qq = idx >> 6;            // kt*12 + nt
  int nt = qq % 12, kt = qq / 12;
  int n = nt * 64 + nr, k = kt * 32 + kk;
  Wq_tiled[o] = (bf16)Wqkv[k * C3_ + n];
}

// ---------------------------------------------------------------------------
// QKV projection, 64x128 tile, 768 gemm blocks + vectorized LDS-restaged
// epilogues (4x b128 stores/thread). 1D grid, m fastest: all n-blocks of an
// m-panel land on the same XCD. Blocks 768..2815 pack rel->rel8; blocks
// 2816..3071 tile Wproj.
// ---------------------------------------------------------------------------
__global__ __launch_bounds__(256) void gemm_qkv(
    const float* __restrict__ A, const bf16* __restrict__ Wq_tiled,
    const float* __restrict__ Wproj, const int* __restrict__ rel,
    bf16* __restrict__ q, bf16* __restrict__ kT, bf16* __restrict__ vT,
    bf16* __restrict__ Wp_tiled, unsigned char* __restrict__ rel8)
{
  __shared__ __align__(16) char sm[18432];

  int bb = blockIdx.x;
  int tid = threadIdx.x;

  if (bb >= 768) {
    if (bb < 2816) {
      // rel pack: 2048 blocks x 256 thr x 16 elems
      long p = ((long)(bb - 768) * 256 + tid) * 16;
      i32x4 a = *reinterpret_cast<const i32x4*>(rel + p);
      i32x4 b2 = *reinterpret_cast<const i32x4*>(rel + p + 4);
      i32x4 c = *reinterpret_cast<const i32x4*>(rel + p + 8);
      i32x4 d = *reinterpret_cast<const i32x4*>(rel + p + 12);
      unsigned o0 = (unsigned)a[0] | ((unsigned)a[1] << 8) | ((unsigned)a[2] << 16) | ((unsigned)a[3] << 24);
      unsigned o1 = (unsigned)b2[0] | ((unsigned)b2[1] << 8) | ((unsigned)b2[2] << 16) | ((unsigned)b2[3] << 24);
      unsigned o2 = (unsigned)c[0] | ((unsigned)c[1] << 8) | ((unsigned)c[2] << 16) | ((unsigned)c[3] << 24);
      unsigned o3 = (unsigned)d[0] | ((unsigned)d[1] << 8) | ((unsigned)d[2] << 16) | ((unsigned)d[3] << 24);
      i32x4 ov = {(int)o0, (int)o1, (int)o2, (int)o3};
      *reinterpret_cast<i32x4*>(rel8 + p) = ov;
    } else {
      int p = (bb - 2816) * 256 + tid;
      int kk = p & 31;
      int n = (p >> 5) & 255;
      int kt = p >> 13;
      Wp_tiled[p] = (bf16)Wproj[(kt * 32 + kk) * C_ + n];
    }
    return;
  }

  bf16 (*As)[40] = (bf16(*)[40])(void*)sm;            // [64][40]
  bf16 (*Bs)[40] = (bf16(*)[40])(void*)(sm + 5120);   // [128][40]

  int wave = tid >> 6, lane = tid & 63, quad = lane >> 4, l16 = lane & 15;
  int x = bb & 127, y = bb >> 7;          // m-tile (64 rows), n-tile (128 cols)
  int m0 = x * 64, n0 = y * 128;
  int msub = (wave & 1) * 32, nsub = (wave >> 1) * 64;

  f32x4 acc[2][4] = {};

  int arow = tid >> 2, akc = (tid & 3) * 8;
  const float* aptr = A + (long)(m0 + arow) * C_ + akc;   // + kt*32
  int bn = tid >> 1, bkc = (tid & 1) * 16;
  const bf16* bptr = Wq_tiled +
      ((long)(y * 2 + (bn >> 6)) * 2048 + (bn & 63) * 32 + bkc);  // + kt*24576

  float4 a0 = *reinterpret_cast<const float4*>(aptr);
  float4 a1 = *reinterpret_cast<const float4*>(aptr + 4);
  i32x4 bv0 = *reinterpret_cast<const i32x4*>(bptr);
  i32x4 bv1 = *reinterpret_cast<const i32x4*>(bptr + 8);

  for (int kt = 0; kt < 8; ++kt) {
    __syncthreads();
    {
      bf16 at[8] = {(bf16)a0.x, (bf16)a0.y, (bf16)a0.z, (bf16)a0.w,
                    (bf16)a1.x, (bf16)a1.y, (bf16)a1.z, (bf16)a1.w};
      *reinterpret_cast<bf16x8*>(&As[arow][akc]) = *reinterpret_cast<bf16x8*>(at);
      *reinterpret_cast<i32x4*>(&Bs[bn][bkc]) = bv0;
      *reinterpret_cast<i32x4*>(&Bs[bn][bkc + 8]) = bv1;
    }
    __syncthreads();

    if (kt < 7) {
      int kn = (kt + 1) * 32;
      a0 = *reinterpret_cast<const float4*>(aptr + kn);
      a1 = *reinterpret_cast<const float4*>(aptr + kn + 4);
      bv0 = *reinterpret_cast<const i32x4*>(bptr + (long)(kt + 1) * 24576);
      bv1 = *reinterpret_cast<const i32x4*>(bptr + (long)(kt + 1) * 24576 + 8);
    }

    bf16x8 af[2], bfr[4];
#pragma unroll
    for (int mi = 0; mi < 2; ++mi)
      af[mi] = *reinterpret_cast<const bf16x8*>(&As[msub + mi * 16 + l16][quad * 8]);
#pragma unroll
    for (int ni = 0; ni < 4; ++ni)
      bfr[ni] = *reinterpret_cast<const bf16x8*>(&Bs[nsub + ni * 16 + l16][quad * 8]);
#pragma unroll
    for (int mi = 0; mi < 2; ++mi)
#pragma unroll
      for (int ni = 0; ni < 4; ++ni)
        acc[mi][ni] = __builtin_amdgcn_mfma_f32_16x16x32_bf16(af[mi], bfr[ni], acc[mi][ni], 0, 0, 0);
  }

  __syncthreads();  // all frag reads done; reuse sm for epilogue staging

  if (y < 4) {
    // q (y<2) and kT (y in {2,3}): stage [64 rows][128 cols] then b128 stores
    float mul = (y < 2) ? SCALE : 1.0f;
    bf16 (*Ep)[136] = (bf16(*)[136])(void*)sm;   // 272B rows, 16B-aligned
#pragma unroll
    for (int mi = 0; mi < 2; ++mi)
#pragma unroll
      for (int ni = 0; ni < 4; ++ni)
#pragma unroll
        for (int r = 0; r < 4; ++r)
          Ep[msub + mi * 16 + quad * 4 + r][nsub + ni * 16 + l16] =
              (bf16)(acc[mi][ni][r] * mul);
    __syncthreads();
    int row = tid >> 2, seg = tid & 3;
    i32x4 w0 = *reinterpret_cast<const i32x4*>(&Ep[row][seg * 32]);
    i32x4 w1 = *reinterpret_cast<const i32x4*>(&Ep[row][seg * 32 + 8]);
    i32x4 w2 = *reinterpret_cast<const i32x4*>(&Ep[row][seg * 32 + 16]);
    i32x4 w3 = *reinterpret_cast<const i32x4*>(&Ep[row][seg * 32 + 24]);
    bf16* dst;
    if (y < 2) {
      dst = q + (long)(m0 + row) * 256 + n0 + seg * 32;
    } else {
      int c = n0 - 256 + seg * 32;       // multiple of 32 -> exactly one h
      int h = c >> 5;
      int gr = m0 + row, b = gr >> 10, n = gr & 1023;
      dst = kT + (((long)(b * H_ + h)) * N_ + n) * 32;
    }
    *reinterpret_cast<i32x4*>(dst) = w0;
    *reinterpret_cast<i32x4*>(dst + 8) = w1;
    *reinterpret_cast<i32x4*>(dst + 16) = w2;
    *reinterpret_cast<i32x4*>(dst + 24) = w3;
  } else {
    // vT (y in {4,5}): transpose + j-perm stage [128 c][64 n'] then b128 stores
    bf16 (*Vls)[72] = (bf16(*)[72])(void*)sm;    // 144B rows, 16B-aligned
#pragma unroll
    for (int mi = 0; mi < 2; ++mi)
#pragma unroll
      for (int ni = 0; ni < 4; ++ni)
#pragma unroll
        for (int r = 0; r < 4; ++r) {
          int nn = msub + mi * 16 + quad * 4 + r;   // 0..63
          int np = (nn & ~31) | ((nn & 12) << 1) | (nn & 3) | (((nn >> 4) & 1) << 2);
          Vls[nsub + ni * 16 + l16][np] = (bf16)acc[mi][ni][r];
        }
    __syncthreads();
    int c = tid >> 1, nseg = (tid & 1) * 32;
    i32x4 w0 = *reinterpret_cast<const i32x4*>(&Vls[c][nseg]);
    i32x4 w1 = *reinterpret_cast<const i32x4*>(&Vls[c][nseg + 8]);
    i32x4 w2 = *reinterpret_cast<const i32x4*>(&Vls[c][nseg + 16]);
    i32x4 w3 = *reinterpret_cast<const i32x4*>(&Vls[c][nseg + 24]);
    int gb = m0 >> 10, mn = m0 & 1023;
    bf16* dst = vT + ((long)(gb * C_ + n0 - 512 + c)) * N_ + mn + nseg;
    *reinterpret_cast<i32x4*>(dst) = w0;
    *reinterpret_cast<i32x4*>(dst + 8) = w1;
    *reinterpret_cast<i32x4*>(dst + 16) = w2;
    *reinterpret_cast<i32x4*>(dst + 24) = w3;
  }
}

// ---------------------------------------------------------------------------
// Flash attention + fused projection — R6-proven structure (replay-verified):
// swapped-QK register softmax, wave-private global_load_lds staging,
// barrier-free j-loop, rel8 TRIPLE-buffered (2-tile reuse distance — the R7
// double-buffer's 1-tile distance raced on warm replays), vmcnt(8) counted
// waits. Only change vs R6: prologue drain vmcnt(2) -> vmcnt(0) (immune to
// GLD issue-order; one-time cost).
// ---------------------------------------------------------------------------
__global__ __launch_bounds__(512) void flash_attn(
    const bf16* __restrict__ q, const bf16* __restrict__ kT,
    const bf16* __restrict__ vT, const unsigned char* __restrict__ rel8,
    const int* __restrict__ rel_len, const float* __restrict__ btab,
    const bf16* __restrict__ Wp_tiled, const float* __restrict__ bias,
    float* __restrict__ out)
{
  __shared__ __align__(16) char smem[78336];
  char* const KB0 = smem;            // [2][8][2048]
  char* const VB0 = smem + 32768;    // [2][8][2048]
  char* const RB0 = smem + 65536;    // [3][8][512]
  float* const ebtl = (float*)(smem + 77824);  // [8][16]

  int tid = threadIdx.x;
  int h = tid >> 6, lane = tid & 63, quad = lane >> 4, l16 = lane & 15;

  // bijective XCD swizzle (512 blocks = 8 XCDs x 64): XCD k -> batch k.
  int wg = blockIdx.y * 64 + blockIdx.x;
  int swz = (wg & 7) * 64 + (wg >> 3);
  int b = swz >> 6, i0 = (swz & 63) * 16;
  long bN = (long)b * N_;

  int mask_len = (int)((float)rel_len[b] * 0.5f);
  if (tid < 80) {
    int t = tid >> 3, hh = tid & 7;
    ebtl[hh * 16 + t] = __expf(btab[t * H_ + hh] + (t > mask_len ? -100.f : 0.f) - FMAX);
  }

  // Q as B-fragment: col = q-row (l16), k = d (quad*8+e)
  bf16x8 qf = *reinterpret_cast<const bf16x8*>(
      q + (bN + i0 + l16) * 256 + h * 32 + quad * 8);

  // ebtl visible + prologue VMEM drained so loop vmcnt counts only DMAs.
  __syncthreads();

  // ---- per-lane DMA source offsets (16B-slot swizzle pre-applied) ----
  int l = lane;
  int sxc = (((l & 3) ^ ((l >> 3) & 3)) << 4);
  int kc0 = (l >> 2) * 64 + sxc;                  // K: row l>>2, 2nd GLD +1024
  int vc0 = (h * 32 + (l >> 2)) * 2048 + sxc;     // V: chan h*32+(l>>2), 2nd +32768
  int rc0 = (l >> 3) * 1024 + (l & 7) * 4;        // rel8: row l>>3, 2nd GLD +8192

  const char* kTb = (const char*)kT + ((long)(b * 8 + h) << 16);  // +t*2048
  const char* vTb = (const char*)vT + (long)b * 524288;           // +t*64
  const char* rb8 = (const char*)rel8 + (bN + i0) * 1024;         // +t*32

  // ---- LDS read offsets ----
  int swq = ((quad ^ ((l16 >> 1) & 3)) << 4);
  int kr = h * 2048 + l16 * 64 + swq;      // K/V: row l16 (+1024: row 16+l16)
  int rr = h * 512 + l16 * 32 + quad * 4;  // rel8: row l16, j=4q (+16: j=16+4q)

#define KB(i) (KB0 + (i) * 16384)
#define VB(i) (VB0 + (i) * 16384)
#define RB(i) (RB0 + (i) * 4096)

#define GLD16(G, L) __builtin_amdgcn_global_load_lds(                         \
    (const __attribute__((address_space(1))) void*)(G),                       \
    (__attribute__((address_space(3))) void*)(L), 16, 0, 0)
#define GLD4(G, L) __builtin_amdgcn_global_load_lds(                          \
    (const __attribute__((address_space(1))) void*)(G),                       \
    (__attribute__((address_space(3))) void*)(L), 4, 0, 0)

#define GATH(G, RV0, RV1) do {                                                \
    _Pragma("unroll")                                                         \
    for (int e = 0; e < 4; ++e) {                                             \
      G[e]     = ebtl[h * 16 + (int)((RV0 >> (8 * e)) & 255u)];               \
      G[4 + e] = ebtl[h * 16 + (int)((RV1 >> (8 * e)) & 255u)];               \
    }                                                                         \
  } while (0)

#define COMP(K0, K1, V0, V1, G) do {                                          \
    f32x4 z = {};                                                             \
    f32x4 s0 = __builtin_amdgcn_mfma_f32_16x16x32_bf16(K0, qf, z, 0, 0, 0);   \
    f32x4 s1 = __builtin_amdgcn_mfma_f32_16x16x32_bf16(K1, qf, z, 0, 0, 0);   \
    bf16x8 pa;                                                                \
    _Pragma("unroll")                                                         \
    for (int e = 0; e < 4; ++e) {                                             \
      float p0 = __expf(s0[e]) * G[e];                                        \
      float p1 = __expf(s1[e]) * G[4 + e];                                    \
      l_acc += p0 + p1;                                                       \
      pa[e] = (bf16)p0;                                                       \
      pa[4 + e] = (bf16)p1;                                                   \
    }                                                                         \
    oacc[0] = __builtin_amdgcn_mfma_f32_16x16x32_bf16(pa, V0, oacc[0], 0, 0, 0); \
    oacc[1] = __builtin_amdgcn_mfma_f32_16x16x32_bf16(pa, V1, oacc[1], 0, 0, 0); \
  } while (0)

// Tile T: issue KV(T+1)->buf KVW, rel8(T+3)->buf RW_; counted wait (own wave
// only!); read KV(T) from KVR + read-ahead rel8(T+1) from RR_; gather GN for
// T+1; compute T with GC. No barriers.
#define TILE(T_, KVR, KVW, RR_, RW_, GC, GN) do {                             \
    int tn_ = ((T_) + 1) & 31, tr_ = ((T_) + 3) & 31;                         \
    GLD16(kTb + tn_ * 2048 + kc0,        KB(KVW) + h * 2048);                 \
    GLD16(kTb + tn_ * 2048 + kc0 + 1024, KB(KVW) + h * 2048 + 1024);          \
    GLD16(vTb + tn_ * 64 + vc0,          VB(KVW) + h * 2048);                 \
    GLD16(vTb + tn_ * 64 + vc0 + 32768,  VB(KVW) + h * 2048 + 1024);          \
    GLD4(rb8 + tr_ * 32 + rc0,           RB(RW_) + h * 512);                  \
    GLD4(rb8 + tr_ * 32 + rc0 + 8192,    RB(RW_) + h * 512 + 256);            \
    asm volatile("s_waitcnt vmcnt(8)" ::: "memory");                          \
    bf16x8 kf0 = *(const bf16x8*)(KB(KVR) + kr);                              \
    bf16x8 kf1 = *(const bf16x8*)(KB(KVR) + kr + 1024);                       \
    bf16x8 vf0 = *(const bf16x8*)(VB(KVR) + kr);                              \
    bf16x8 vf1 = *(const bf16x8*)(VB(KVR) + kr + 1024);                       \
    unsigned rv0 = *(const unsigned*)(RB(RR_) + rr);                          \
    unsigned rv1 = *(const unsigned*)(RB(RR_) + rr + 16);                     \
    GATH(GN, rv0, rv1);                                                       \
    COMP(kf0, kf1, vf0, vf1, GC);                                             \
  } while (0)

  f32x4 oacc[2] = {};
  float l_acc = 0.f;
  float gA[8], gB[8];

  // ---- prologue: KV(0)->buf0; rel8(0,1,2)->rbuf 0,1,2; gather gA(0).
  GLD16(kTb + kc0,        KB(0) + h * 2048);
  GLD16(kTb + kc0 + 1024, KB(0) + h * 2048 + 1024);
  GLD16(vTb + vc0,          VB(0) + h * 2048);
  GLD16(vTb + vc0 + 32768,  VB(0) + h * 2048 + 1024);
  GLD4(rb8 + rc0,             RB(0) + h * 512);
  GLD4(rb8 + rc0 + 8192,      RB(0) + h * 512 + 256);
  GLD4(rb8 + 32 + rc0,        RB(1) + h * 512);
  GLD4(rb8 + 32 + rc0 + 8192, RB(1) + h * 512 + 256);
  GLD4(rb8 + 64 + rc0,        RB(2) + h * 512);
  GLD4(rb8 + 64 + rc0 + 8192, RB(2) + h * 512 + 256);
  asm volatile("s_waitcnt vmcnt(0)" ::: "memory");  // full drain: order-proof
  {
    unsigned rv0 = *(const unsigned*)(RB(0) + rr);
    unsigned rv1 = *(const unsigned*)(RB(0) + rr + 16);
    GATH(gA, rv0, rv1);
  }

  // KV bufs: (T&1 read, (T+1)&1 write); rel8: read-ahead (T+1)%3, write (T+3)%3.
#pragma unroll 1
  for (int t = 0; t < 30; t += 6) {
    TILE(t + 0, 0, 1, 1, 0, gA, gB);
    TILE(t + 1, 1, 0, 2, 1, gB, gA);
    TILE(t + 2, 0, 1, 0, 2, gA, gB);
    TILE(t + 3, 1, 0, 1, 0, gB, gA);
    TILE(t + 4, 0, 1, 2, 1, gA, gB);
    TILE(t + 5, 1, 0, 0, 2, gB, gA);
  }
  TILE(30, 0, 1, 1, 0, gA, gB);
  TILE(31, 1, 0, 2, 1, gB, gA);
#undef TILE
#undef COMP
#undef GATH
#undef GLD16
#undef GLD4
#undef KB
#undef VB
#undef RB

  // drain wrapped tail DMAs before aliasing smem as attL
  asm volatile("s_waitcnt vmcnt(0)" ::: "memory");
  __syncthreads();

  // row sums: lane's p's are all for q-row l16 -> reduce across quads.
  float lsum = l_acc;
  lsum += __shfl_xor(lsum, 16);
  lsum += __shfl_xor(lsum, 32);
  float inv = 1.f / lsum;   // inv for q-row = l16

  bf16 (*attL)[264] = (bf16(*)[264])(void*)smem;
#pragma unroll
  for (int r = 0; r < 4; ++r) {
    float invr = __shfl(inv, quad * 4 + r);
    attL[quad * 4 + r][h * 32 + l16] = (bf16)(oacc[0][r] * invr);
    attL[quad * 4 + r][h * 32 + 16 + l16] = (bf16)(oacc[1][r] * invr);
  }
  __syncthreads();

  // fused projection: wave h computes out[16 rows][h*32 .. h*32+31]
  f32x4 pacc[2] = {};
  const bf16* wp = Wp_tiled + ((h * 32 + l16) * 32 + quad * 8);  // + kt*8192, +512 for ni=1
#pragma unroll
  for (int kt = 0; kt < 8; ++kt) {
    bf16x8 afr = *reinterpret_cast<const bf16x8*>(&attL[l16][kt * 32 + quad * 8]);
    bf16x8 b0 = *reinterpret_cast<const bf16x8*>(wp + kt * 8192);
    bf16x8 b1 = *reinterpret_cast<const bf16x8*>(wp + kt * 8192 + 512);
    pacc[0] = __builtin_amdgcn_mfma_f32_16x16x32_bf16(afr, b0, pacc[0], 0, 0, 0);
    pacc[1] = __builtin_amdgcn_mfma_f32_16x16x32_bf16(afr, b1, pacc[1], 0, 0, 0);
  }
  float bi0 = bias[h * 32 + l16];
  float bi1 = bias[h * 32 + 16 + l16];
#pragma unroll
  for (int r = 0; r < 4; ++r) {
    long rowoff = (bN + i0 + quad * 4 + r) * C_ + h * 32;
    out[rowoff + l16] = pacc[0][r] + bi0;
    out[rowoff + 16 + l16] = pacc[1][r] + bi1;
  }
}

// ---------------------------------------------------------------------------
extern "C" void kernel_launch(void* const* d_in, const int* in_sizes, int n_in,
                              void* d_out, int out_size, void* d_ws, size_t ws_size,
                              hipStream_t stream) {
  const float* X     = (const float*)d_in[0];   // att_embedding [8,1024,256] fp32
  const int*   rel   = (const int*)d_in[1];     // relation_position [8,1024,1024]
  const int*   rlen  = (const int*)d_in[2];     // rel_len [8]
  const float* Wqkv  = (const float*)d_in[3];   // [256,768] fp32
  const float* Wproj = (const float*)d_in[4];   // [256,256] fp32
  const float* bproj = (const float*)d_in[5];   // [256] fp32
  const float* btab  = (const float*)d_in[6];   // [10,8] fp32
  float* out = (float*)d_out;                   // [8,1024,256] fp32

  char* ws = (char*)d_ws;
  bf16* Wq_tiled = (bf16*)ws;                            // 393216 B
  bf16* Wp_tiled = (bf16*)(ws + 393216);                 // 131072 B
  bf16* q  = (bf16*)(ws + 524288);                       // 4 MiB
  bf16* kT = (bf16*)(ws + 524288 + 4194304);             // 4 MiB
  bf16* vT = (bf16*)(ws + 524288 + 2 * 4194304);         // 4 MiB
  unsigned char* rel8 = (unsigned char*)(ws + 13107200); // 8 MiB

  prep<<<dim3(768), 256, 0, stream>>>(Wqkv, Wq_tiled);
  gemm_qkv<<<dim3(3072), 256, 0, stream>>>(X, Wq_tiled, Wproj, rel,
                                           q, kT, vT, Wp_tiled, rel8);
  flash_attn<<<dim3(N_ / 16, B_), 512, 0, stream>>>(
      q, kT, vT, rel8, rlen, btab, Wp_tiled, bproj, out);
}